// Round 2
// baseline (220.690 us; speedup 1.0000x reference)
//
#include <hip/hip_runtime.h>
#include <stdint.h>

#define SEQ    4096
#define EMBED  1024
#define NHEAD  16
#define HDIM   64
#define WIN    256
#define BSZ    2
#define M_TOT  (BSZ * SEQ)   // 8192
#define N_QKV  3072
#define N_QK   2048
#define K_DIM  1024
#define LOG2E  1.4426950408889634f

typedef __attribute__((ext_vector_type(8))) __bf16 bf16x8;
typedef __attribute__((ext_vector_type(4))) float  f32x4;

__device__ __forceinline__ unsigned short f2bf(float f) {
  union { float f; unsigned int u; } c; c.f = f;
  unsigned int u = c.u;
  unsigned int r = (u + 0x7FFFu + ((u >> 16) & 1u)) >> 16;
  return (unsigned short)r;
}

// packed f32x2 -> bf16x2 (RNE, same as f2bf) in ONE VALU instr
__device__ __forceinline__ unsigned int cvt_pk_bf16(float lo, float hi) {
  unsigned int r;
  asm("v_cvt_pk_bf16_f32 %0, %1, %2" : "=v"(r) : "v"(lo), "v"(hi));
  return r;
}

__device__ __forceinline__ void gl2lds16(const void* g, void* l) {
  __builtin_amdgcn_global_load_lds((const __attribute__((address_space(1))) void*)g,
                                   (__attribute__((address_space(3))) void*)l, 16, 0, 0);
}

// ---------------- fp32 -> bf16 cast of hidden_states ----------------
__global__ __launch_bounds__(256) void cvt_h(const float* __restrict__ in,
                                             unsigned short* __restrict__ out) {
  int i = (blockIdx.x * 256 + threadIdx.x) * 4;
  float4 v = *(const float4*)(in + i);
  ushort4 o;
  o.x = f2bf(v.x); o.y = f2bf(v.y); o.z = f2bf(v.z); o.w = f2bf(v.w);
  *(ushort4*)(out + i) = o;
}

// ------- transpose + cast weights: Wt[n_global][k] = W_sel[k][n] -------
__global__ __launch_bounds__(256) void cvt_w(const float* __restrict__ Wq,
                                             const float* __restrict__ Wk,
                                             const float* __restrict__ Wv,
                                             unsigned short* __restrict__ Wt) {
  __shared__ float t[32][33];
  int z = blockIdx.z;
  const float* W = (z == 0) ? Wq : (z == 1) ? Wk : Wv;
  int kb = blockIdx.x * 32, nb = blockIdx.y * 32;
  int tx = threadIdx.x, ty = threadIdx.y;  // block (32,8)
  for (int it = 0; it < 4; ++it) {
    int k = kb + ty + it * 8;
    t[ty + it * 8][tx] = W[(size_t)k * 1024 + nb + tx];
  }
  __syncthreads();
  for (int it = 0; it < 4; ++it) {
    int n = nb + ty + it * 8;
    Wt[(size_t)(z * 1024 + n) * 1024 + kb + tx] = f2bf(t[tx][ty + it * 8]);
  }
}

// ---- fused QKV GEMM: 256x256 tile, BK=64, 8 waves (2Mx4N), double-buffered
// 2-phase pipeline (stage tile t+1 while computing tile t; one barrier/iter).
// XOR-swizzled staging (pre-swizzled GLOBAL addr + swizzled ds_read — LDS side
// of global_load_lds stays linear base + lane*16). Bijective XCD swizzle of the
// flat block id (384 % 8 == 0). R2 rewrite of the 128x128 2-barrier version:
// MfmaUtil was 28% with ~45% of each iter spent in the staging vmcnt(0) drain.
__global__ __launch_bounds__(512, 2) void qkv_gemm(const unsigned short* __restrict__ A,   // h bf16 [8192][1024]
                                                   const unsigned short* __restrict__ Bt,  // Wt [3072][1024]
                                                   const float* __restrict__ bq,
                                                   const float* __restrict__ bk,
                                                   const float* __restrict__ bv,
                                                   unsigned short* __restrict__ C,         // qk [8192][2048]
                                                   unsigned short* __restrict__ Vt) {      // vtg [2048][4096]
  __shared__ unsigned short As[2][256 * 64];
  __shared__ unsigned short Bs[2][256 * 64];
  int tid  = threadIdx.x;
  int lane = tid & 63, wave = tid >> 6;          // 8 waves
  int ln   = lane & 15, quad = lane >> 4;
  // bijective XCD swizzle: 384 blocks, 48 per XCD, contiguous chunk each
  int flat = blockIdx.y * 12 + blockIdx.x;       // 0..383
  int swz  = (flat & 7) * 48 + (flat >> 3);
  int m0 = (swz / 12) * 256, n0 = (swz % 12) * 256;
  int wy = wave >> 2, wx = wave & 3;             // 2 x 4 wave grid
  f32x4 acc[8][4];
  for (int i = 0; i < 8; ++i)
    for (int j = 0; j < 4; ++j) acc[i][j] = (f32x4){0.f, 0.f, 0.f, 0.f};

  // stage one 256x64 A-tile + B-tile into buffer `buf` (8 gl2lds / thread)
#define STAGE(buf, k0)                                                          \
  do {                                                                          \
    for (int sweep = 0; sweep < 4; ++sweep) {                                   \
      int chunk = sweep * 512 + tid;            /* 0..2047 */                   \
      int row = chunk >> 3, c = chunk & 7;                                      \
      int cg = c ^ (row & 7);                                                   \
      gl2lds16(A + (size_t)(m0 + row) * K_DIM + (k0) + cg * 8,                  \
               &As[buf][chunk * 8]);                                            \
    }                                                                           \
    for (int sweep = 0; sweep < 4; ++sweep) {                                   \
      int chunk = sweep * 512 + tid;                                            \
      int row = chunk >> 3, c = chunk & 7;                                      \
      int cg = c ^ (row & 7);                                                   \
      gl2lds16(Bt + (size_t)(n0 + row) * K_DIM + (k0) + cg * 8,                 \
               &Bs[buf][chunk * 8]);                                            \
    }                                                                           \
  } while (0)

  STAGE(0, 0);
  __syncthreads();                               // drains vmcnt(0) + barrier

  for (int t = 0; t < 16; ++t) {
    int cur = t & 1;
    if (t < 15) { STAGE(cur ^ 1, (t + 1) * 64); }   // prefetch next tile, other buf
    const unsigned short* as = As[cur];
    const unsigned short* bs = Bs[cur];
    for (int ks2 = 0; ks2 < 2; ++ks2) {
      bf16x8 af[8], bfr[4];
      for (int i = 0; i < 8; ++i) {
        int row = wy * 128 + i * 16 + ln;
        int c = (ks2 * 4 + quad) ^ (row & 7);
        af[i] = *(const bf16x8*)&as[row * 64 + c * 8];
      }
      for (int j = 0; j < 4; ++j) {
        int row = wx * 64 + j * 16 + ln;
        int c = (ks2 * 4 + quad) ^ (row & 7);
        bfr[j] = *(const bf16x8*)&bs[row * 64 + c * 8];
      }
      __builtin_amdgcn_s_setprio(1);
      for (int i = 0; i < 8; ++i)
        for (int j = 0; j < 4; ++j)
          acc[i][j] = __builtin_amdgcn_mfma_f32_16x16x32_bf16(af[i], bfr[j], acc[i][j], 0, 0, 0);
      __builtin_amdgcn_s_setprio(0);
    }
    __syncthreads();                             // drain staging DMA + barrier
  }
#undef STAGE

  if (n0 < N_QK) {
    for (int j = 0; j < 4; ++j) {
      int n = n0 + wx * 64 + j * 16 + ln;
      float bias, scl;
      if (n < 1024) { bias = bq[n];        scl = 0.125f * LOG2E; }  // fold 1/sqrt(64) and log2(e)
      else          { bias = bk[n - 1024]; scl = 1.f; }
      for (int i = 0; i < 8; ++i) {
        int mb = m0 + wy * 128 + i * 16 + quad * 4;
        for (int r = 0; r < 4; ++r) {
          float v = (acc[i][j][r] + bias) * scl;
          C[(size_t)(mb + r) * N_QK + n] = f2bf(v);
        }
      }
    }
  } else {
    for (int j = 0; j < 4; ++j) {
      int n  = n0 + wx * 64 + j * 16 + ln;   // 2048..3071
      int hd = n - 2048;                     // head*64 + d
      float bias = bv[hd];
      for (int i = 0; i < 8; ++i) {
        int mb  = m0 + wy * 128 + i * 16 + quad * 4;
        int bb  = mb >> 12;                  // / SEQ
        int pos = mb & (SEQ - 1);
        ushort4 pk;
        pk.x = f2bf(acc[i][j][0] + bias);
        pk.y = f2bf(acc[i][j][1] + bias);
        pk.z = f2bf(acc[i][j][2] + bias);
        pk.w = f2bf(acc[i][j][3] + bias);
        *(ushort4*)&Vt[((size_t)bb * (NHEAD * HDIM) + hd) * SEQ + pos] = pk;
      }
    }
  }
}

// ------- banded flash attention: 64 q / block, shuffle-P (no P LDS round trip) -------
// O^T = V^T * P: P B-fragments are built from the S^T C-regs via cross-lane shuffles
// (nt = 2ks + (quad>>1); src quads (quad&1)*2, (quad&1)*2+1). 2 barriers/tile.
// O^T C-layout (col=q=ln) -> per-lane 1/l (no shuffle) + float4 output stores.
// R1: v_cvt_pk_bf16_f32 P-packing, s_setprio around MFMA clusters, bijective XCD
//     swizzle of blockIdx.x. (passed, total 225.5 -> 209.9 us)
__global__ __launch_bounds__(256) void attn(const unsigned short* __restrict__ qk,
                                            const unsigned short* __restrict__ vtg,
                                            float* __restrict__ out) {
  __shared__ unsigned short Kl[64 * 72];
  __shared__ unsigned short Vl[64 * 72];
  int tid  = threadIdx.x;
  int lane = tid & 63, wave = tid >> 6;          // wave 0..3, 16 queries each
  int ln   = lane & 15, quad = lane >> 4;
  int bx = blockIdx.x;
  int lx = ((bx & 7) << 3) | (bx >> 3);
  int q0 = lx * 64, head = blockIdx.y, b = blockIdx.z;
  size_t baseRow = (size_t)b * SEQ;
  const unsigned short* kptr = qk + 1024;
  const unsigned short* vrow = vtg + ((size_t)(b * NHEAD + head) * HDIM) * SEQ;

  // per-thread staging coordinates (constant across tiles)
  int sy = tid >> 3, sc = tid & 7;               // row 0..31, 16B chunk 0..7
  const unsigned short* kbase = kptr + (baseRow + sy) * (size_t)N_QK + head * HDIM + sc * 8;
  const unsigned short* vbase = vrow + (size_t)sy * SEQ + sc * 8;

  // Q fragments from global (B-operand: n=q=ln, k = ks*32 + quad*8 + j)
  bf16x8 qf[2];
  {
    size_t ro = (baseRow + q0 + wave * 16 + ln) * (size_t)N_QK + head * HDIM + quad * 8;
    qf[0] = *(const bf16x8*)&qk[ro];
    qf[1] = *(const bf16x8*)&qk[ro + 32];
  }

  float l_st = 0.f;
  f32x4 o_acc[4];                                // O^T: row d = dt*16+quad*4+r, col q = ln
  for (int dt = 0; dt < 4; ++dt) o_acc[dt] = (f32x4){0.f, 0.f, 0.f, 0.f};

  int lo = (q0 >= 256) ? 0 : (256 - q0) / 64;
  int hi = (SEQ + 256 - q0) / 64; if (hi > 9) hi = 9;

  uint4 pk0, pk1, pv0, pv1;
#define PREFETCH(KT)                                                        \
  {                                                                         \
    pk0 = *(const uint4*)&kbase[(size_t)(KT) * N_QK];                       \
    pk1 = *(const uint4*)&kbase[(size_t)((KT) + 32) * N_QK];                \
    pv0 = *(const uint4*)&vbase[(KT)];                                      \
    pv1 = *(const uint4*)&vbase[(size_t)32 * SEQ + (KT)];                   \
  }

  PREFETCH(q0 - 256 + lo * 64);

  int srcA = ((lane & 16) << 1) | ln;            // (quad&1)*32 + ln
  int srcB = srcA + 16;
  bool hiQ = (lane & 32) != 0;                   // quad >= 2

  for (int t = lo; t < hi; ++t) {
    int kt = q0 - 256 + t * 64;
    __syncthreads();                                   // A: prev-tile LDS reads drained
    *(uint4*)&Kl[sy * 72 + sc * 8]        = pk0;
    *(uint4*)&Kl[(sy + 32) * 72 + sc * 8] = pk1;
    *(uint4*)&Vl[sy * 72 + sc * 8]        = pv0;
    *(uint4*)&Vl[(sy + 32) * 72 + sc * 8] = pv1;
    __syncthreads();                                   // B: staging visible

    if (t + 1 < hi) { PREFETCH(kt + 64); }             // hide HBM latency behind compute

    // S^T = K Q^T : row k = kt + nt*16 + quad*4 + r, col q = ln  (kf loaded JIT)
    f32x4 s[4];
    __builtin_amdgcn_s_setprio(1);
    for (int nt = 0; nt < 4; ++nt) {
      bf16x8 kf0 = *(const bf16x8*)&Kl[(nt * 16 + ln) * 72 + quad * 8];
      bf16x8 kf1 = *(const bf16x8*)&Kl[(nt * 16 + ln) * 72 + 32 + quad * 8];
      f32x4 z = (f32x4){0.f, 0.f, 0.f, 0.f};
      z = __builtin_amdgcn_mfma_f32_16x16x32_bf16(kf0, qf[0], z, 0, 0, 0);
      z = __builtin_amdgcn_mfma_f32_16x16x32_bf16(kf1, qf[1], z, 0, 0, 0);
      s[nt] = z;
    }
    __builtin_amdgcn_s_setprio(0);

    if (t == 0 || t == 8) {                            // only edge offsets need band mask
      int qq = q0 + wave * 16 + ln;
      for (int nt = 0; nt < 4; ++nt) {
        int kb = kt + nt * 16 + quad * 4 - qq;
        for (int r = 0; r < 4; ++r) {
          int dd = kb + r;
          if (dd < -WIN || dd > WIN) s[nt][r] = -INFINITY;
        }
      }
    }

    // fixed-max softmax (scores in log2 units; masked -> exp2(-inf) = 0)
    float rs = 0.f;
    for (int nt = 0; nt < 4; ++nt)
      for (int r = 0; r < 4; ++r) {
        float p = exp2f(s[nt][r]);
        s[nt][r] = p;
        rs += p;
      }
    l_st += rs;

    // pack P to bf16 pairs (per nt: elements 0,1 and 2,3) — one v_cvt_pk each
    unsigned int p01[4], p23[4];
    for (int nt = 0; nt < 4; ++nt) {
      p01[nt] = cvt_pk_bf16(s[nt][0], s[nt][1]);
      p23[nt] = cvt_pk_bf16(s[nt][2], s[nt][3]);
    }

    // O^T += V^T P : A = V^T [d][k] from Vl, B = P[k][q] built via shuffles
    for (int ks = 0; ks < 2; ++ks) {
      int ntA = 2 * ks, ntB = 2 * ks + 1;
      unsigned int a0 = (unsigned int)__shfl((int)p01[ntA], srcA);
      unsigned int a1 = (unsigned int)__shfl((int)p23[ntA], srcA);
      unsigned int a2 = (unsigned int)__shfl((int)p01[ntA], srcB);
      unsigned int a3 = (unsigned int)__shfl((int)p23[ntA], srcB);
      unsigned int b0 = (unsigned int)__shfl((int)p01[ntB], srcA);
      unsigned int b1 = (unsigned int)__shfl((int)p23[ntB], srcA);
      unsigned int b2 = (unsigned int)__shfl((int)p01[ntB], srcB);
      unsigned int b3 = (unsigned int)__shfl((int)p23[ntB], srcB);
      union { uint4 u; bf16x8 v; } pf;
      pf.u.x = hiQ ? b0 : a0;
      pf.u.y = hiQ ? b1 : a1;
      pf.u.z = hiQ ? b2 : a2;
      pf.u.w = hiQ ? b3 : a3;
      __builtin_amdgcn_s_setprio(1);
      for (int dt = 0; dt < 4; ++dt) {
        bf16x8 vf = *(const bf16x8*)&Vl[(dt * 16 + ln) * 72 + ks * 32 + quad * 8];
        o_acc[dt] = __builtin_amdgcn_mfma_f32_16x16x32_bf16(vf, pf.v, o_acc[dt], 0, 0, 0);
      }
      __builtin_amdgcn_s_setprio(0);
    }
  }

  // l reduction across the 4 quads of column q=ln; per-lane inverse, float4 stores
  float l = l_st;
  l += __shfl_xor(l, 16);
  l += __shfl_xor(l, 32);
  float inv = 1.0f / l;
  int qpos = q0 + wave * 16 + ln;
  float* ob = out + (baseRow + qpos) * (size_t)EMBED + head * HDIM + quad * 4;
  for (int dt = 0; dt < 4; ++dt) {
    float4 v;
    v.x = o_acc[dt][0] * inv;
    v.y = o_acc[dt][1] * inv;
    v.z = o_acc[dt][2] * inv;
    v.w = o_acc[dt][3] * inv;
    *(float4*)(ob + dt * 16) = v;
  }
#undef PREFETCH
}

extern "C" void kernel_launch(void* const* d_in, const int* in_sizes, int n_in,
                              void* d_out, int out_size, void* d_ws, size_t ws_size,
                              hipStream_t stream) {
  const float* h  = (const float*)d_in[0];
  const float* Wq = (const float*)d_in[1];
  const float* bq = (const float*)d_in[2];
  const float* Wk = (const float*)d_in[3];
  const float* bk = (const float*)d_in[4];
  const float* Wv = (const float*)d_in[5];
  const float* bv = (const float*)d_in[6];
  float* out = (float*)d_out;

  unsigned short* h_bf  = (unsigned short*)d_ws;                 // 16 MB
  unsigned short* wt_bf = h_bf + (size_t)M_TOT * K_DIM;          //  6 MB
  unsigned short* qk    = wt_bf + (size_t)N_QKV * K_DIM;         // 32 MB
  unsigned short* vtg   = qk + (size_t)M_TOT * N_QK;             // 16 MB  (total 70 MB)

  cvt_h<<<(M_TOT * K_DIM) / 1024, 256, 0, stream>>>(h, h_bf);
  cvt_w<<<dim3(32, 32, 3), dim3(32, 8), 0, stream>>>(Wq, Wk, Wv, wt_bf);
  qkv_gemm<<<dim3(12, 32), 512, 0, stream>>>(h_bf, wt_bf, bq, bk, bv, qk, vtg);
  attn<<<dim3(SEQ / 64, NHEAD, BSZ), 256, 0, stream>>>(qk, vtg, out);
}

// Round 3
// 214.484 us; speedup vs baseline: 1.0289x; 1.0289x over previous
//
#include <hip/hip_runtime.h>
#include <stdint.h>

#define SEQ    4096
#define EMBED  1024
#define NHEAD  16
#define HDIM   64
#define WIN    256
#define BSZ    2
#define M_TOT  (BSZ * SEQ)   // 8192
#define N_QKV  3072
#define N_QK   2048
#define K_DIM  1024
#define LOG2E  1.4426950408889634f

typedef __attribute__((ext_vector_type(8))) __bf16 bf16x8;
typedef __attribute__((ext_vector_type(4))) float  f32x4;

__device__ __forceinline__ unsigned short f2bf(float f) {
  union { float f; unsigned int u; } c; c.f = f;
  unsigned int u = c.u;
  unsigned int r = (u + 0x7FFFu + ((u >> 16) & 1u)) >> 16;
  return (unsigned short)r;
}

// packed f32x2 -> bf16x2 (RNE, same as f2bf) in ONE VALU instr
__device__ __forceinline__ unsigned int cvt_pk_bf16(float lo, float hi) {
  unsigned int r;
  asm("v_cvt_pk_bf16_f32 %0, %1, %2" : "=v"(r) : "v"(lo), "v"(hi));
  return r;
}

__device__ __forceinline__ void gl2lds16(const void* g, void* l) {
  __builtin_amdgcn_global_load_lds((const __attribute__((address_space(1))) void*)g,
                                   (__attribute__((address_space(3))) void*)l, 16, 0, 0);
}

// ---------------- fp32 -> bf16 cast of hidden_states ----------------
__global__ __launch_bounds__(256) void cvt_h(const float* __restrict__ in,
                                             unsigned short* __restrict__ out) {
  int i = (blockIdx.x * 256 + threadIdx.x) * 4;
  float4 v = *(const float4*)(in + i);
  ushort4 o;
  o.x = f2bf(v.x); o.y = f2bf(v.y); o.z = f2bf(v.z); o.w = f2bf(v.w);
  *(ushort4*)(out + i) = o;
}

// ------- transpose + cast weights: Wt[n_global][k] = W_sel[k][n] -------
__global__ __launch_bounds__(256) void cvt_w(const float* __restrict__ Wq,
                                             const float* __restrict__ Wk,
                                             const float* __restrict__ Wv,
                                             unsigned short* __restrict__ Wt) {
  __shared__ float t[32][33];
  int z = blockIdx.z;
  const float* W = (z == 0) ? Wq : (z == 1) ? Wk : Wv;
  int kb = blockIdx.x * 32, nb = blockIdx.y * 32;
  int tx = threadIdx.x, ty = threadIdx.y;  // block (32,8)
  for (int it = 0; it < 4; ++it) {
    int k = kb + ty + it * 8;
    t[ty + it * 8][tx] = W[(size_t)k * 1024 + nb + tx];
  }
  __syncthreads();
  for (int it = 0; it < 4; ++it) {
    int n = nb + ty + it * 8;
    Wt[(size_t)(z * 1024 + n) * 1024 + kb + tx] = f2bf(t[tx][ty + it * 8]);
  }
}

// ---- fused QKV GEMM: 256x256, BK=64, 8 waves (2Mx4N), 8-phase counted-vmcnt
// schedule (T3+T4). 4 phases per K-tile, each phase: {ds_read subtile || stage
// 1 region via global_load_lds} -> s_barrier -> setprio(1) 16xMFMA setprio(0)
// -> s_barrier. vmcnt(6) ONCE per K-tile (3 regions in flight), never 0 in the
// main loop — raw s_barrier everywhere (no __syncthreads = no vmcnt(0) drain).
// Region ledger (race-free, one-phase-behind overwrite):
//   reads:  p0: A-lo+B-lo frags   p1: B-hi   p2: A-hi   p3: (regs only)
//   stages: p0: A-hi(t+1)  p1: A-lo(t+2)  p2: B-lo(t+2)  p3: B-hi(t+2)
// A-frags live across {p0,p1}, B-frags across {p0..p3} -> 24 ds_read_b128 per
// K-tile per wave (minimum). XOR-swizzle (T2) as before: pre-swizzled GLOBAL
// address + swizzled ds_read, LDS side of global_load_lds stays linear.
__global__ __launch_bounds__(512, 2) void qkv_gemm(const unsigned short* __restrict__ A,   // h bf16 [8192][1024]
                                                   const unsigned short* __restrict__ Bt,  // Wt [3072][1024]
                                                   const float* __restrict__ bq,
                                                   const float* __restrict__ bk,
                                                   const float* __restrict__ bv,
                                                   unsigned short* __restrict__ C,         // qk [8192][2048]
                                                   unsigned short* __restrict__ Vt) {      // vtg [2048][4096]
  __shared__ unsigned short As[2][256 * 64];
  __shared__ unsigned short Bs[2][256 * 64];
  int tid  = threadIdx.x;
  int lane = tid & 63, wave = tid >> 6;          // 8 waves
  int ln   = lane & 15, quad = lane >> 4;
  // bijective XCD swizzle: 384 blocks, 48 contiguous per XCD
  int flat = blockIdx.y * 12 + blockIdx.x;       // 0..383
  int swz  = (flat & 7) * 48 + (flat >> 3);
  int m0 = (swz / 12) * 256, n0 = (swz % 12) * 256;
  int wy = wave >> 2, wx = wave & 3;             // 2 x 4 wave grid
  f32x4 acc[8][4];
#pragma unroll
  for (int i = 0; i < 8; ++i)
#pragma unroll
    for (int j = 0; j < 4; ++j) acc[i][j] = (f32x4){0.f, 0.f, 0.f, 0.f};

  // staging constants: region = 128 rows x 64 cols (16KB) = 2 sweeps of
  // 512 thr x 16B. A region rows: half h -> {h*64..h*64+63, 128+h*64..}.
  // B region rows: 4 strips of 32 per wx: h -> {wx*64+h*32 .. +32}.
  int c8 = tid & 7;
  int aR[2][2], bR[2][2];                        // [half][sweep] LDS row
#pragma unroll
  for (int s = 0; s < 2; ++s) {
    int rir = s * 64 + (tid >> 3);               // 0..127
    int la = (rir & 63) | ((rir & 64) << 1);
    int lb = (rir & 31) | ((rir >> 5) << 6);
    aR[0][s] = la;  aR[1][s] = la + 64;
    bR[0][s] = lb;  bR[1][s] = lb + 32;
  }

#define STG_A(buf, half, kt)                                                     \
  do {                                                                           \
    _Pragma("unroll")                                                            \
    for (int s = 0; s < 2; ++s) {                                                \
      int lr = aR[half][s]; int cg = c8 ^ (lr & 7);                              \
      gl2lds16(A + (size_t)(m0 + lr) * K_DIM + (kt) * 64 + cg * 8,               \
               &As[buf][lr * 64 + c8 * 8]);                                      \
    }                                                                            \
  } while (0)
#define STG_B(buf, half, kt)                                                     \
  do {                                                                           \
    _Pragma("unroll")                                                            \
    for (int s = 0; s < 2; ++s) {                                                \
      int lr = bR[half][s]; int cg = c8 ^ (lr & 7);                              \
      gl2lds16(Bt + (size_t)(n0 + lr) * K_DIM + (kt) * 64 + cg * 8,              \
               &Bs[buf][lr * 64 + c8 * 8]);                                      \
    }                                                                            \
  } while (0)

  // prologue: K0 {A-lo,B-lo,B-hi,A-hi} + K1 {A-lo,B-lo,B-hi}; drain to 6
  // (= K0 fully landed, K1's 3 regions in flight) — steady-state pattern.
  STG_A(0, 0, 0); STG_B(0, 0, 0); STG_B(0, 1, 0); STG_A(0, 1, 0);
  STG_A(1, 0, 1); STG_B(1, 0, 1); STG_B(1, 1, 1);
  asm volatile("s_waitcnt vmcnt(6)" ::: "memory");
  __builtin_amdgcn_s_barrier();

  bf16x8 af[4][2], bv0[2][2], bv1[2][2];
  int aBase = wy * 128, bBase = wx * 64;

#pragma unroll 1
  for (int t = 0; t < 16; ++t) {
    int cur = t & 1;
    const unsigned short* as = As[cur];
    const unsigned short* bs = Bs[cur];

    // ---- phase 0: ds_read A-lo + B-lo frags; stage A-hi(t+1); MFMA q(0,0)
#pragma unroll
    for (int i2 = 0; i2 < 4; ++i2) {
      int row = aBase + i2 * 16 + ln;
#pragma unroll
      for (int ks = 0; ks < 2; ++ks) {
        int c = (ks * 4 + quad) ^ (row & 7);
        af[i2][ks] = *(const bf16x8*)&as[row * 64 + c * 8];
      }
    }
#pragma unroll
    for (int j2 = 0; j2 < 2; ++j2) {
      int row = bBase + j2 * 16 + ln;
#pragma unroll
      for (int ks = 0; ks < 2; ++ks) {
        int c = (ks * 4 + quad) ^ (row & 7);
        bv0[j2][ks] = *(const bf16x8*)&bs[row * 64 + c * 8];
      }
    }
    if (t < 15) STG_A(cur ^ 1, 1, t + 1);
    __builtin_amdgcn_s_barrier();
    __builtin_amdgcn_s_setprio(1);
#pragma unroll
    for (int ks = 0; ks < 2; ++ks)
#pragma unroll
      for (int i2 = 0; i2 < 4; ++i2)
#pragma unroll
        for (int j2 = 0; j2 < 2; ++j2)
          acc[i2][j2] = __builtin_amdgcn_mfma_f32_16x16x32_bf16(af[i2][ks], bv0[j2][ks], acc[i2][j2], 0, 0, 0);
    __builtin_amdgcn_s_setprio(0);
    __builtin_amdgcn_s_barrier();

    // ---- phase 1: ds_read B-hi frags; stage A-lo(t+2); MFMA q(0,1)
#pragma unroll
    for (int j2 = 0; j2 < 2; ++j2) {
      int row = bBase + 32 + j2 * 16 + ln;
#pragma unroll
      for (int ks = 0; ks < 2; ++ks) {
        int c = (ks * 4 + quad) ^ (row & 7);
        bv1[j2][ks] = *(const bf16x8*)&bs[row * 64 + c * 8];
      }
    }
    if (t < 14) STG_A(cur, 0, t + 2);
    __builtin_amdgcn_s_barrier();
    __builtin_amdgcn_s_setprio(1);
#pragma unroll
    for (int ks = 0; ks < 2; ++ks)
#pragma unroll
      for (int i2 = 0; i2 < 4; ++i2)
#pragma unroll
        for (int j2 = 0; j2 < 2; ++j2)
          acc[i2][2 + j2] = __builtin_amdgcn_mfma_f32_16x16x32_bf16(af[i2][ks], bv1[j2][ks], acc[i2][2 + j2], 0, 0, 0);
    __builtin_amdgcn_s_setprio(0);
    __builtin_amdgcn_s_barrier();

    // ---- phase 2: ds_read A-hi frags (af reuse); stage B-lo(t+2); MFMA q(1,0)
#pragma unroll
    for (int i2 = 0; i2 < 4; ++i2) {
      int row = aBase + 64 + i2 * 16 + ln;
#pragma unroll
      for (int ks = 0; ks < 2; ++ks) {
        int c = (ks * 4 + quad) ^ (row & 7);
        af[i2][ks] = *(const bf16x8*)&as[row * 64 + c * 8];
      }
    }
    if (t < 14) STG_B(cur, 0, t + 2);
    __builtin_amdgcn_s_barrier();
    __builtin_amdgcn_s_setprio(1);
#pragma unroll
    for (int ks = 0; ks < 2; ++ks)
#pragma unroll
      for (int i2 = 0; i2 < 4; ++i2)
#pragma unroll
        for (int j2 = 0; j2 < 2; ++j2)
          acc[4 + i2][j2] = __builtin_amdgcn_mfma_f32_16x16x32_bf16(af[i2][ks], bv0[j2][ks], acc[4 + i2][j2], 0, 0, 0);
    __builtin_amdgcn_s_setprio(0);
    __builtin_amdgcn_s_barrier();

    // ---- phase 3: stage B-hi(t+2); MFMA q(1,1); vmcnt(6) checkpoint
    if (t < 14) STG_B(cur, 1, t + 2);
    __builtin_amdgcn_s_barrier();
    __builtin_amdgcn_s_setprio(1);
#pragma unroll
    for (int ks = 0; ks < 2; ++ks)
#pragma unroll
      for (int i2 = 0; i2 < 4; ++i2)
#pragma unroll
        for (int j2 = 0; j2 < 2; ++j2)
          acc[4 + i2][2 + j2] = __builtin_amdgcn_mfma_f32_16x16x32_bf16(af[i2][ks], bv1[j2][ks], acc[4 + i2][2 + j2], 0, 0, 0);
    __builtin_amdgcn_s_setprio(0);
    asm volatile("s_waitcnt vmcnt(6)" ::: "memory");
    __builtin_amdgcn_s_barrier();
  }
#undef STG_A
#undef STG_B

  if (n0 < N_QK) {
#pragma unroll
    for (int j = 0; j < 4; ++j) {
      int n = n0 + wx * 64 + j * 16 + ln;
      float bias, scl;
      if (n < 1024) { bias = bq[n];        scl = 0.125f * LOG2E; }  // fold 1/sqrt(64) and log2(e)
      else          { bias = bk[n - 1024]; scl = 1.f; }
#pragma unroll
      for (int i = 0; i < 8; ++i) {
        int mb = m0 + wy * 128 + i * 16 + quad * 4;
#pragma unroll
        for (int r = 0; r < 4; ++r) {
          float v = (acc[i][j][r] + bias) * scl;
          C[(size_t)(mb + r) * N_QK + n] = f2bf(v);
        }
      }
    }
  } else {
#pragma unroll
    for (int j = 0; j < 4; ++j) {
      int n  = n0 + wx * 64 + j * 16 + ln;   // 2048..3071
      int hd = n - 2048;                     // head*64 + d
      float bias = bv[hd];
#pragma unroll
      for (int i = 0; i < 8; ++i) {
        int mb  = m0 + wy * 128 + i * 16 + quad * 4;
        int bb  = mb >> 12;                  // / SEQ
        int pos = mb & (SEQ - 1);
        ushort4 pk;
        pk.x = f2bf(acc[i][j][0] + bias);
        pk.y = f2bf(acc[i][j][1] + bias);
        pk.z = f2bf(acc[i][j][2] + bias);
        pk.w = f2bf(acc[i][j][3] + bias);
        *(ushort4*)&Vt[((size_t)bb * (NHEAD * HDIM) + hd) * SEQ + pos] = pk;
      }
    }
  }
}

// ------- banded flash attention: 64 q / block, shuffle-P (no P LDS round trip) -------
// O^T = V^T * P: P B-fragments are built from the S^T C-regs via cross-lane shuffles
// (nt = 2ks + (quad>>1); src quads (quad&1)*2, (quad&1)*2+1). 2 barriers/tile.
// O^T C-layout (col=q=ln) -> per-lane 1/l (no shuffle) + float4 output stores.
// R1: v_cvt_pk_bf16_f32 P-packing, s_setprio around MFMA clusters, bijective XCD
//     swizzle of blockIdx.x. (passed, total 225.5 -> 209.9 us)
__global__ __launch_bounds__(256) void attn(const unsigned short* __restrict__ qk,
                                            const unsigned short* __restrict__ vtg,
                                            float* __restrict__ out) {
  __shared__ unsigned short Kl[64 * 72];
  __shared__ unsigned short Vl[64 * 72];
  int tid  = threadIdx.x;
  int lane = tid & 63, wave = tid >> 6;          // wave 0..3, 16 queries each
  int ln   = lane & 15, quad = lane >> 4;
  int bx = blockIdx.x;
  int lx = ((bx & 7) << 3) | (bx >> 3);
  int q0 = lx * 64, head = blockIdx.y, b = blockIdx.z;
  size_t baseRow = (size_t)b * SEQ;
  const unsigned short* kptr = qk + 1024;
  const unsigned short* vrow = vtg + ((size_t)(b * NHEAD + head) * HDIM) * SEQ;

  // per-thread staging coordinates (constant across tiles)
  int sy = tid >> 3, sc = tid & 7;               // row 0..31, 16B chunk 0..7
  const unsigned short* kbase = kptr + (baseRow + sy) * (size_t)N_QK + head * HDIM + sc * 8;
  const unsigned short* vbase = vrow + (size_t)sy * SEQ + sc * 8;

  // Q fragments from global (B-operand: n=q=ln, k = ks*32 + quad*8 + j)
  bf16x8 qf[2];
  {
    size_t ro = (baseRow + q0 + wave * 16 + ln) * (size_t)N_QK + head * HDIM + quad * 8;
    qf[0] = *(const bf16x8*)&qk[ro];
    qf[1] = *(const bf16x8*)&qk[ro + 32];
  }

  float l_st = 0.f;
  f32x4 o_acc[4];                                // O^T: row d = dt*16+quad*4+r, col q = ln
  for (int dt = 0; dt < 4; ++dt) o_acc[dt] = (f32x4){0.f, 0.f, 0.f, 0.f};

  int lo = (q0 >= 256) ? 0 : (256 - q0) / 64;
  int hi = (SEQ + 256 - q0) / 64; if (hi > 9) hi = 9;

  uint4 pk0, pk1, pv0, pv1;
#define PREFETCH(KT)                                                        \
  {                                                                         \
    pk0 = *(const uint4*)&kbase[(size_t)(KT) * N_QK];                       \
    pk1 = *(const uint4*)&kbase[(size_t)((KT) + 32) * N_QK];                \
    pv0 = *(const uint4*)&vbase[(KT)];                                      \
    pv1 = *(const uint4*)&vbase[(size_t)32 * SEQ + (KT)];                   \
  }

  PREFETCH(q0 - 256 + lo * 64);

  int srcA = ((lane & 16) << 1) | ln;            // (quad&1)*32 + ln
  int srcB = srcA + 16;
  bool hiQ = (lane & 32) != 0;                   // quad >= 2

  for (int t = lo; t < hi; ++t) {
    int kt = q0 - 256 + t * 64;
    __syncthreads();                                   // A: prev-tile LDS reads drained
    *(uint4*)&Kl[sy * 72 + sc * 8]        = pk0;
    *(uint4*)&Kl[(sy + 32) * 72 + sc * 8] = pk1;
    *(uint4*)&Vl[sy * 72 + sc * 8]        = pv0;
    *(uint4*)&Vl[(sy + 32) * 72 + sc * 8] = pv1;
    __syncthreads();                                   // B: staging visible

    if (t + 1 < hi) { PREFETCH(kt + 64); }             // hide HBM latency behind compute

    // S^T = K Q^T : row k = kt + nt*16 + quad*4 + r, col q = ln  (kf loaded JIT)
    f32x4 s[4];
    __builtin_amdgcn_s_setprio(1);
    for (int nt = 0; nt < 4; ++nt) {
      bf16x8 kf0 = *(const bf16x8*)&Kl[(nt * 16 + ln) * 72 + quad * 8];
      bf16x8 kf1 = *(const bf16x8*)&Kl[(nt * 16 + ln) * 72 + 32 + quad * 8];
      f32x4 z = (f32x4){0.f, 0.f, 0.f, 0.f};
      z = __builtin_amdgcn_mfma_f32_16x16x32_bf16(kf0, qf[0], z, 0, 0, 0);
      z = __builtin_amdgcn_mfma_f32_16x16x32_bf16(kf1, qf[1], z, 0, 0, 0);
      s[nt] = z;
    }
    __builtin_amdgcn_s_setprio(0);

    if (t == 0 || t == 8) {                            // only edge offsets need band mask
      int qq = q0 + wave * 16 + ln;
      for (int nt = 0; nt < 4; ++nt) {
        int kb = kt + nt * 16 + quad * 4 - qq;
        for (int r = 0; r < 4; ++r) {
          int dd = kb + r;
          if (dd < -WIN || dd > WIN) s[nt][r] = -INFINITY;
        }
      }
    }

    // fixed-max softmax (scores in log2 units; masked -> exp2(-inf) = 0)
    float rs = 0.f;
    for (int nt = 0; nt < 4; ++nt)
      for (int r = 0; r < 4; ++r) {
        float p = exp2f(s[nt][r]);
        s[nt][r] = p;
        rs += p;
      }
    l_st += rs;

    // pack P to bf16 pairs (per nt: elements 0,1 and 2,3) — one v_cvt_pk each
    unsigned int p01[4], p23[4];
    for (int nt = 0; nt < 4; ++nt) {
      p01[nt] = cvt_pk_bf16(s[nt][0], s[nt][1]);
      p23[nt] = cvt_pk_bf16(s[nt][2], s[nt][3]);
    }

    // O^T += V^T P : A = V^T [d][k] from Vl, B = P[k][q] built via shuffles
    for (int ks = 0; ks < 2; ++ks) {
      int ntA = 2 * ks, ntB = 2 * ks + 1;
      unsigned int a0 = (unsigned int)__shfl((int)p01[ntA], srcA);
      unsigned int a1 = (unsigned int)__shfl((int)p23[ntA], srcA);
      unsigned int a2 = (unsigned int)__shfl((int)p01[ntA], srcB);
      unsigned int a3 = (unsigned int)__shfl((int)p23[ntA], srcB);
      unsigned int b0 = (unsigned int)__shfl((int)p01[ntB], srcA);
      unsigned int b1 = (unsigned int)__shfl((int)p23[ntB], srcA);
      unsigned int b2 = (unsigned int)__shfl((int)p01[ntB], srcB);
      unsigned int b3 = (unsigned int)__shfl((int)p23[ntB], srcB);
      union { uint4 u; bf16x8 v; } pf;
      pf.u.x = hiQ ? b0 : a0;
      pf.u.y = hiQ ? b1 : a1;
      pf.u.z = hiQ ? b2 : a2;
      pf.u.w = hiQ ? b3 : a3;
      __builtin_amdgcn_s_setprio(1);
      for (int dt = 0; dt < 4; ++dt) {
        bf16x8 vf = *(const bf16x8*)&Vl[(dt * 16 + ln) * 72 + ks * 32 + quad * 8];
        o_acc[dt] = __builtin_amdgcn_mfma_f32_16x16x32_bf16(vf, pf.v, o_acc[dt], 0, 0, 0);
      }
      __builtin_amdgcn_s_setprio(0);
    }
  }

  // l reduction across the 4 quads of column q=ln; per-lane inverse, float4 stores
  float l = l_st;
  l += __shfl_xor(l, 16);
  l += __shfl_xor(l, 32);
  float inv = 1.0f / l;
  int qpos = q0 + wave * 16 + ln;
  float* ob = out + (baseRow + qpos) * (size_t)EMBED + head * HDIM + quad * 4;
  for (int dt = 0; dt < 4; ++dt) {
    float4 v;
    v.x = o_acc[dt][0] * inv;
    v.y = o_acc[dt][1] * inv;
    v.z = o_acc[dt][2] * inv;
    v.w = o_acc[dt][3] * inv;
    *(float4*)(ob + dt * 16) = v;
  }
#undef PREFETCH
}

extern "C" void kernel_launch(void* const* d_in, const int* in_sizes, int n_in,
                              void* d_out, int out_size, void* d_ws, size_t ws_size,
                              hipStream_t stream) {
  const float* h  = (const float*)d_in[0];
  const float* Wq = (const float*)d_in[1];
  const float* bq = (const float*)d_in[2];
  const float* Wk = (const float*)d_in[3];
  const float* bk = (const float*)d_in[4];
  const float* Wv = (const float*)d_in[5];
  const float* bv = (const float*)d_in[6];
  float* out = (float*)d_out;

  unsigned short* h_bf  = (unsigned short*)d_ws;                 // 16 MB
  unsigned short* wt_bf = h_bf + (size_t)M_TOT * K_DIM;          //  6 MB
  unsigned short* qk    = wt_bf + (size_t)N_QKV * K_DIM;         // 32 MB
  unsigned short* vtg   = qk + (size_t)M_TOT * N_QK;             // 16 MB  (total 70 MB)

  cvt_h<<<(M_TOT * K_DIM) / 1024, 256, 0, stream>>>(h, h_bf);
  cvt_w<<<dim3(32, 32, 3), dim3(32, 8), 0, stream>>>(Wq, Wk, Wv, wt_bf);
  qkv_gemm<<<dim3(12, 32), 512, 0, stream>>>(h_bf, wt_bf, bq, bk, bv, qk, vtg);
  attn<<<dim3(SEQ / 64, NHEAD, BSZ), 256, 0, stream>>>(qk, vtg, out);
}

// Round 4
// 207.292 us; speedup vs baseline: 1.0646x; 1.0347x over previous
//
#include <hip/hip_runtime.h>
#include <stdint.h>

#define SEQ    4096
#define EMBED  1024
#define NHEAD  16
#define HDIM   64
#define WIN    256
#define BSZ    2
#define M_TOT  (BSZ * SEQ)   // 8192
#define N_QKV  3072
#define N_QK   2048
#define K_DIM  1024
#define LOG2E  1.4426950408889634f

typedef __attribute__((ext_vector_type(8))) __bf16 bf16x8;
typedef __attribute__((ext_vector_type(4))) float  f32x4;

__device__ __forceinline__ unsigned short f2bf(float f) {
  union { float f; unsigned int u; } c; c.f = f;
  unsigned int u = c.u;
  unsigned int r = (u + 0x7FFFu + ((u >> 16) & 1u)) >> 16;
  return (unsigned short)r;
}

// packed f32x2 -> bf16x2 (RNE, same as f2bf) in ONE VALU instr
__device__ __forceinline__ unsigned int cvt_pk_bf16(float lo, float hi) {
  unsigned int r;
  asm("v_cvt_pk_bf16_f32 %0, %1, %2" : "=v"(r) : "v"(lo), "v"(hi));
  return r;
}

__device__ __forceinline__ void gl2lds16(const void* g, void* l) {
  __builtin_amdgcn_global_load_lds((const __attribute__((address_space(1))) void*)g,
                                   (__attribute__((address_space(3))) void*)l, 16, 0, 0);
}

// ---- merged cast kernel: blocks [0,8192) convert hidden_states (fp32->bf16),
// blocks [8192, 8192+3072) transpose+cast the three weight matrices. One launch
// instead of two (probing the kernel-sum vs dur_us gap = launch overhead).
__global__ __launch_bounds__(256) void cvt_all(const float* __restrict__ in,
                                               unsigned short* __restrict__ out,
                                               const float* __restrict__ Wq,
                                               const float* __restrict__ Wk,
                                               const float* __restrict__ Wv,
                                               unsigned short* __restrict__ Wt) {
  __shared__ float t[32][33];
  int tid = threadIdx.x;
  if (blockIdx.x < 8192) {
    int i = (blockIdx.x * 256 + tid) * 4;
    float4 v = *(const float4*)(in + i);
    ushort4 o;
    o.x = f2bf(v.x); o.y = f2bf(v.y); o.z = f2bf(v.z); o.w = f2bf(v.w);
    *(ushort4*)(out + i) = o;
  } else {
    int wb = blockIdx.x - 8192;                  // 0..3071
    int z  = wb >> 10;                           // 0..2
    int rem = wb & 1023;
    int kb = (rem & 31) * 32, nb = (rem >> 5) * 32;
    const float* W = (z == 0) ? Wq : (z == 1) ? Wk : Wv;
    int tx = tid & 31, ty = tid >> 5;            // (32,8)
    for (int it = 0; it < 4; ++it) {
      int k = kb + ty + it * 8;
      t[ty + it * 8][tx] = W[(size_t)k * 1024 + nb + tx];
    }
    __syncthreads();
    for (int it = 0; it < 4; ++it) {
      int n = nb + ty + it * 8;
      Wt[(size_t)(z * 1024 + n) * 1024 + kb + tx] = f2bf(t[tx][ty + it * 8]);
    }
  }
}

// ---- fused QKV GEMM: 128(M)x256(N) tile, BK=64, 8 waves (2Mx4N), 8-phase
// counted-vmcnt schedule (T3+T4) + T2 XOR-swizzle + T5 setprio.
// R4: tile changed from 256x256 (384 blocks = 1.5 rounds on 256 CUs, 25% of
// CU-rounds idle) to 128x256 -> grid 768 = EXACTLY 3 rounds. R3's within-block
// rate was ~890 TF (669 measured x 512/384); this keeps the schedule and
// removes the tail. LDS 96KB (2dbuf x (A 16K + B 32K)), acc[4][4] per wave.
// Ledger (race-free): regions A(2 instr), B-lo(2), B-hi(2) per K-tile.
//   p0: read af(8)+bv0(4); stage B-hi(t+1)->buf^1; barrier; MFMA j01; barrier
//   p1: read bv1(4); stage A(t+2)+B-lo(t+2)->cur (last read p0, barrier
//       passed; cur's B-hi read this phase is NOT staged here); barrier;
//       MFMA j23; vmcnt(4) [newest-4 = t+2 stages -> t+1 fully landed]; barrier
__global__ __launch_bounds__(512, 2) void qkv_gemm(const unsigned short* __restrict__ A,   // h bf16 [8192][1024]
                                                   const unsigned short* __restrict__ Bt,  // Wt [3072][1024]
                                                   const float* __restrict__ bq,
                                                   const float* __restrict__ bk,
                                                   const float* __restrict__ bv,
                                                   unsigned short* __restrict__ C,         // qk [8192][2048]
                                                   unsigned short* __restrict__ Vt) {      // vtg [2048][4096]
  __shared__ unsigned short As[2][128 * 64];
  __shared__ unsigned short Bs[2][256 * 64];
  int tid  = threadIdx.x;
  int lane = tid & 63, wave = tid >> 6;          // 8 waves
  int ln   = lane & 15, quad = lane >> 4;
  // bijective XCD swizzle: 768 blocks, 96 contiguous per XCD
  int flat = blockIdx.y * 12 + blockIdx.x;       // 0..767
  int swz  = (flat & 7) * 96 + (flat >> 3);
  int m0 = (swz / 12) * 128, n0 = (swz % 12) * 256;
  int wy = wave >> 2, wx = wave & 3;             // 2 x 4 wave grid; per-wave 64x64
  f32x4 acc[4][4];
#pragma unroll
  for (int i = 0; i < 4; ++i)
#pragma unroll
    for (int j = 0; j < 4; ++j) acc[i][j] = (f32x4){0.f, 0.f, 0.f, 0.f};

  // staging: regions of 128 rows x 64 cols (16KB) = 2 sweeps of 512thr x 16B
  int c8 = tid & 7;
  int sRow[2];                                   // per-sweep row 0..127
#pragma unroll
  for (int s = 0; s < 2; ++s) sRow[s] = s * 64 + (tid >> 3);

#define STG_A(buf, kt)                                                           \
  do {                                                                           \
    _Pragma("unroll")                                                            \
    for (int s = 0; s < 2; ++s) {                                                \
      int lr = sRow[s]; int cg = c8 ^ (lr & 7);                                  \
      gl2lds16(A + (size_t)(m0 + lr) * K_DIM + (kt) * 64 + cg * 8,               \
               &As[buf][lr * 512 + c8 * 8]);                                     \
    }                                                                            \
  } while (0)
#define STG_BLO(buf, kt)                                                         \
  do {                                                                           \
    _Pragma("unroll")                                                            \
    for (int s = 0; s < 2; ++s) {                                                \
      int lr = sRow[s]; int cg = c8 ^ (lr & 7);                                  \
      gl2lds16(Bt + (size_t)(n0 + lr) * K_DIM + (kt) * 64 + cg * 8,              \
               &Bs[buf][lr * 512 + c8 * 8]);                                     \
    }                                                                            \
  } while (0)
#define STG_BHI(buf, kt)                                                         \
  do {                                                                           \
    _Pragma("unroll")                                                            \
    for (int s = 0; s < 2; ++s) {                                                \
      int lr = sRow[s]; int cg = c8 ^ (lr & 7);                                  \
      gl2lds16(Bt + (size_t)(n0 + 128 + lr) * K_DIM + (kt) * 64 + cg * 8,        \
               &Bs[buf][128 * 512 + lr * 512 + c8 * 8]);                         \
    }                                                                            \
  } while (0)
  // NOTE: row stride in LDS is 64 elems = 128 B; lr*512 is in BYTES/2? No:
  // ushort index = lr*64 elems... (see corrected indexing below)

#undef STG_A
#undef STG_BLO
#undef STG_BHI
#define STG_A(buf, kt)                                                           \
  do {                                                                           \
    _Pragma("unroll")                                                            \
    for (int s = 0; s < 2; ++s) {                                                \
      int lr = sRow[s]; int cg = c8 ^ (lr & 7);                                  \
      gl2lds16(A + (size_t)(m0 + lr) * K_DIM + (kt) * 64 + cg * 8,               \
               &As[buf][lr * 64 + c8 * 8]);                                      \
    }                                                                            \
  } while (0)
#define STG_BLO(buf, kt)                                                         \
  do {                                                                           \
    _Pragma("unroll")                                                            \
    for (int s = 0; s < 2; ++s) {                                                \
      int lr = sRow[s]; int cg = c8 ^ (lr & 7);                                  \
      gl2lds16(Bt + (size_t)(n0 + lr) * K_DIM + (kt) * 64 + cg * 8,              \
               &Bs[buf][lr * 64 + c8 * 8]);                                      \
    }                                                                            \
  } while (0)
#define STG_BHI(buf, kt)                                                         \
  do {                                                                           \
    _Pragma("unroll")                                                            \
    for (int s = 0; s < 2; ++s) {                                                \
      int lr = sRow[s]; int cg = c8 ^ (lr & 7);                                  \
      gl2lds16(Bt + (size_t)(n0 + 128 + lr) * K_DIM + (kt) * 64 + cg * 8,        \
               &Bs[buf][(128 + lr) * 64 + c8 * 8]);                              \
    }                                                                            \
  } while (0)

  // prologue: K0 all three regions + K1 {A, B-lo}; vmcnt(4) = K0 landed,
  // K1's A/B-lo in flight (steady-state pattern; t=0 p0 stages B-hi(1)).
  STG_A(0, 0); STG_BLO(0, 0); STG_BHI(0, 0);
  STG_A(1, 1); STG_BLO(1, 1);
  asm volatile("s_waitcnt vmcnt(4)" ::: "memory");
  __builtin_amdgcn_s_barrier();

  bf16x8 af[4][2], bv0[2][2], bv1[2][2];
  int aBase = wy * 64, bBase = wx * 64;

#pragma unroll 1
  for (int t = 0; t < 16; ++t) {
    int cur = t & 1;
    const unsigned short* as = As[cur];
    const unsigned short* bs = Bs[cur];

    // ---- phase 0: read A frags + B-lo frags; stage B-hi(t+1) -> buf^1
#pragma unroll
    for (int i2 = 0; i2 < 4; ++i2) {
      int row = aBase + i2 * 16 + ln;
#pragma unroll
      for (int ks = 0; ks < 2; ++ks) {
        int c = (ks * 4 + quad) ^ (row & 7);
        af[i2][ks] = *(const bf16x8*)&as[row * 64 + c * 8];
      }
    }
#pragma unroll
    for (int j2 = 0; j2 < 2; ++j2) {
      int row = bBase + j2 * 16 + ln;
#pragma unroll
      for (int ks = 0; ks < 2; ++ks) {
        int c = (ks * 4 + quad) ^ (row & 7);
        bv0[j2][ks] = *(const bf16x8*)&bs[row * 64 + c * 8];
      }
    }
    if (t < 15) STG_BHI(cur ^ 1, t + 1);
    __builtin_amdgcn_s_barrier();
    __builtin_amdgcn_s_setprio(1);
#pragma unroll
    for (int ks = 0; ks < 2; ++ks)
#pragma unroll
      for (int i2 = 0; i2 < 4; ++i2)
#pragma unroll
        for (int j2 = 0; j2 < 2; ++j2)
          acc[i2][j2] = __builtin_amdgcn_mfma_f32_16x16x32_bf16(af[i2][ks], bv0[j2][ks], acc[i2][j2], 0, 0, 0);
    __builtin_amdgcn_s_setprio(0);
    __builtin_amdgcn_s_barrier();

    // ---- phase 1: read B-hi frags; stage A(t+2)+B-lo(t+2) -> cur; MFMA j23
#pragma unroll
    for (int j2 = 0; j2 < 2; ++j2) {
      int row = bBase + 32 + j2 * 16 + ln;
#pragma unroll
      for (int ks = 0; ks < 2; ++ks) {
        int c = (ks * 4 + quad) ^ (row & 7);
        bv1[j2][ks] = *(const bf16x8*)&bs[row * 64 + c * 8];
      }
    }
    if (t < 14) { STG_A(cur, t + 2); STG_BLO(cur, t + 2); }
    __builtin_amdgcn_s_barrier();
    __builtin_amdgcn_s_setprio(1);
#pragma unroll
    for (int ks = 0; ks < 2; ++ks)
#pragma unroll
      for (int i2 = 0; i2 < 4; ++i2)
#pragma unroll
        for (int j2 = 0; j2 < 2; ++j2)
          acc[i2][2 + j2] = __builtin_amdgcn_mfma_f32_16x16x32_bf16(af[i2][ks], bv1[j2][ks], acc[i2][2 + j2], 0, 0, 0);
    __builtin_amdgcn_s_setprio(0);
    if (t < 14) asm volatile("s_waitcnt vmcnt(4)" ::: "memory");
    else        asm volatile("s_waitcnt vmcnt(0)" ::: "memory");
    __builtin_amdgcn_s_barrier();
  }
#undef STG_A
#undef STG_BLO
#undef STG_BHI

  if (n0 < N_QK) {
#pragma unroll
    for (int j = 0; j < 4; ++j) {
      int n = n0 + wx * 64 + j * 16 + ln;
      float bias, scl;
      if (n < 1024) { bias = bq[n];        scl = 0.125f * LOG2E; }  // fold 1/sqrt(64) and log2(e)
      else          { bias = bk[n - 1024]; scl = 1.f; }
#pragma unroll
      for (int i = 0; i < 4; ++i) {
        int mb = m0 + wy * 64 + i * 16 + quad * 4;
#pragma unroll
        for (int r = 0; r < 4; ++r) {
          float v = (acc[i][j][r] + bias) * scl;
          C[(size_t)(mb + r) * N_QK + n] = f2bf(v);
        }
      }
    }
  } else {
#pragma unroll
    for (int j = 0; j < 4; ++j) {
      int n  = n0 + wx * 64 + j * 16 + ln;   // 2048..3071
      int hd = n - 2048;                     // head*64 + d
      float bias = bv[hd];
#pragma unroll
      for (int i = 0; i < 4; ++i) {
        int mb  = m0 + wy * 64 + i * 16 + quad * 4;
        int bb  = mb >> 12;                  // / SEQ
        int pos = mb & (SEQ - 1);
        ushort4 pk;
        pk.x = f2bf(acc[i][j][0] + bias);
        pk.y = f2bf(acc[i][j][1] + bias);
        pk.z = f2bf(acc[i][j][2] + bias);
        pk.w = f2bf(acc[i][j][3] + bias);
        *(ushort4*)&Vt[((size_t)bb * (NHEAD * HDIM) + hd) * SEQ + pos] = pk;
      }
    }
  }
}

// ------- banded flash attention: 64 q / block, shuffle-P (no P LDS round trip) -------
// O^T = V^T * P: P B-fragments are built from the S^T C-regs via cross-lane shuffles
// (nt = 2ks + (quad>>1); src quads (quad&1)*2, (quad&1)*2+1). 2 barriers/tile.
// O^T C-layout (col=q=ln) -> per-lane 1/l (no shuffle) + float4 output stores.
// R1: v_cvt_pk_bf16_f32 P-packing, s_setprio around MFMA clusters, bijective XCD
//     swizzle of blockIdx.x. (passed; frozen as control since R1)
__global__ __launch_bounds__(256) void attn(const unsigned short* __restrict__ qk,
                                            const unsigned short* __restrict__ vtg,
                                            float* __restrict__ out) {
  __shared__ unsigned short Kl[64 * 72];
  __shared__ unsigned short Vl[64 * 72];
  int tid  = threadIdx.x;
  int lane = tid & 63, wave = tid >> 6;          // wave 0..3, 16 queries each
  int ln   = lane & 15, quad = lane >> 4;
  int bx = blockIdx.x;
  int lx = ((bx & 7) << 3) | (bx >> 3);
  int q0 = lx * 64, head = blockIdx.y, b = blockIdx.z;
  size_t baseRow = (size_t)b * SEQ;
  const unsigned short* kptr = qk + 1024;
  const unsigned short* vrow = vtg + ((size_t)(b * NHEAD + head) * HDIM) * SEQ;

  // per-thread staging coordinates (constant across tiles)
  int sy = tid >> 3, sc = tid & 7;               // row 0..31, 16B chunk 0..7
  const unsigned short* kbase = kptr + (baseRow + sy) * (size_t)N_QK + head * HDIM + sc * 8;
  const unsigned short* vbase = vrow + (size_t)sy * SEQ + sc * 8;

  // Q fragments from global (B-operand: n=q=ln, k = ks*32 + quad*8 + j)
  bf16x8 qf[2];
  {
    size_t ro = (baseRow + q0 + wave * 16 + ln) * (size_t)N_QK + head * HDIM + quad * 8;
    qf[0] = *(const bf16x8*)&qk[ro];
    qf[1] = *(const bf16x8*)&qk[ro + 32];
  }

  float l_st = 0.f;
  f32x4 o_acc[4];                                // O^T: row d = dt*16+quad*4+r, col q = ln
  for (int dt = 0; dt < 4; ++dt) o_acc[dt] = (f32x4){0.f, 0.f, 0.f, 0.f};

  int lo = (q0 >= 256) ? 0 : (256 - q0) / 64;
  int hi = (SEQ + 256 - q0) / 64; if (hi > 9) hi = 9;

  uint4 pk0, pk1, pv0, pv1;
#define PREFETCH(KT)                                                        \
  {                                                                         \
    pk0 = *(const uint4*)&kbase[(size_t)(KT) * N_QK];                       \
    pk1 = *(const uint4*)&kbase[(size_t)((KT) + 32) * N_QK];                \
    pv0 = *(const uint4*)&vbase[(KT)];                                      \
    pv1 = *(const uint4*)&vbase[(size_t)32 * SEQ + (KT)];                   \
  }

  PREFETCH(q0 - 256 + lo * 64);

  int srcA = ((lane & 16) << 1) | ln;            // (quad&1)*32 + ln
  int srcB = srcA + 16;
  bool hiQ = (lane & 32) != 0;                   // quad >= 2

  for (int t = lo; t < hi; ++t) {
    int kt = q0 - 256 + t * 64;
    __syncthreads();                                   // A: prev-tile LDS reads drained
    *(uint4*)&Kl[sy * 72 + sc * 8]        = pk0;
    *(uint4*)&Kl[(sy + 32) * 72 + sc * 8] = pk1;
    *(uint4*)&Vl[sy * 72 + sc * 8]        = pv0;
    *(uint4*)&Vl[(sy + 32) * 72 + sc * 8] = pv1;
    __syncthreads();                                   // B: staging visible

    if (t + 1 < hi) { PREFETCH(kt + 64); }             // hide HBM latency behind compute

    // S^T = K Q^T : row k = kt + nt*16 + quad*4 + r, col q = ln  (kf loaded JIT)
    f32x4 s[4];
    __builtin_amdgcn_s_setprio(1);
    for (int nt = 0; nt < 4; ++nt) {
      bf16x8 kf0 = *(const bf16x8*)&Kl[(nt * 16 + ln) * 72 + quad * 8];
      bf16x8 kf1 = *(const bf16x8*)&Kl[(nt * 16 + ln) * 72 + 32 + quad * 8];
      f32x4 z = (f32x4){0.f, 0.f, 0.f, 0.f};
      z = __builtin_amdgcn_mfma_f32_16x16x32_bf16(kf0, qf[0], z, 0, 0, 0);
      z = __builtin_amdgcn_mfma_f32_16x16x32_bf16(kf1, qf[1], z, 0, 0, 0);
      s[nt] = z;
    }
    __builtin_amdgcn_s_setprio(0);

    if (t == 0 || t == 8) {                            // only edge offsets need band mask
      int qq = q0 + wave * 16 + ln;
      for (int nt = 0; nt < 4; ++nt) {
        int kb = kt + nt * 16 + quad * 4 - qq;
        for (int r = 0; r < 4; ++r) {
          int dd = kb + r;
          if (dd < -WIN || dd > WIN) s[nt][r] = -INFINITY;
        }
      }
    }

    // fixed-max softmax (scores in log2 units; masked -> exp2(-inf) = 0)
    float rs = 0.f;
    for (int nt = 0; nt < 4; ++nt)
      for (int r = 0; r < 4; ++r) {
        float p = exp2f(s[nt][r]);
        s[nt][r] = p;
        rs += p;
      }
    l_st += rs;

    // pack P to bf16 pairs (per nt: elements 0,1 and 2,3) — one v_cvt_pk each
    unsigned int p01[4], p23[4];
    for (int nt = 0; nt < 4; ++nt) {
      p01[nt] = cvt_pk_bf16(s[nt][0], s[nt][1]);
      p23[nt] = cvt_pk_bf16(s[nt][2], s[nt][3]);
    }

    // O^T += V^T P : A = V^T [d][k] from Vl, B = P[k][q] built via shuffles
    for (int ks = 0; ks < 2; ++ks) {
      int ntA = 2 * ks, ntB = 2 * ks + 1;
      unsigned int a0 = (unsigned int)__shfl((int)p01[ntA], srcA);
      unsigned int a1 = (unsigned int)__shfl((int)p23[ntA], srcA);
      unsigned int a2 = (unsigned int)__shfl((int)p01[ntA], srcB);
      unsigned int a3 = (unsigned int)__shfl((int)p23[ntA], srcB);
      unsigned int b0 = (unsigned int)__shfl((int)p01[ntB], srcA);
      unsigned int b1 = (unsigned int)__shfl((int)p23[ntB], srcA);
      unsigned int b2 = (unsigned int)__shfl((int)p01[ntB], srcB);
      unsigned int b3 = (unsigned int)__shfl((int)p23[ntB], srcB);
      union { uint4 u; bf16x8 v; } pf;
      pf.u.x = hiQ ? b0 : a0;
      pf.u.y = hiQ ? b1 : a1;
      pf.u.z = hiQ ? b2 : a2;
      pf.u.w = hiQ ? b3 : a3;
      __builtin_amdgcn_s_setprio(1);
      for (int dt = 0; dt < 4; ++dt) {
        bf16x8 vf = *(const bf16x8*)&Vl[(dt * 16 + ln) * 72 + ks * 32 + quad * 8];
        o_acc[dt] = __builtin_amdgcn_mfma_f32_16x16x32_bf16(vf, pf.v, o_acc[dt], 0, 0, 0);
      }
      __builtin_amdgcn_s_setprio(0);
    }
  }

  // l reduction across the 4 quads of column q=ln; per-lane inverse, float4 stores
  float l = l_st;
  l += __shfl_xor(l, 16);
  l += __shfl_xor(l, 32);
  float inv = 1.0f / l;
  int qpos = q0 + wave * 16 + ln;
  float* ob = out + (baseRow + qpos) * (size_t)EMBED + head * HDIM + quad * 4;
  for (int dt = 0; dt < 4; ++dt) {
    float4 v;
    v.x = o_acc[dt][0] * inv;
    v.y = o_acc[dt][1] * inv;
    v.z = o_acc[dt][2] * inv;
    v.w = o_acc[dt][3] * inv;
    *(float4*)(ob + dt * 16) = v;
  }
#undef PREFETCH
}

extern "C" void kernel_launch(void* const* d_in, const int* in_sizes, int n_in,
                              void* d_out, int out_size, void* d_ws, size_t ws_size,
                              hipStream_t stream) {
  const float* h  = (const float*)d_in[0];
  const float* Wq = (const float*)d_in[1];
  const float* bq = (const float*)d_in[2];
  const float* Wk = (const float*)d_in[3];
  const float* bk = (const float*)d_in[4];
  const float* Wv = (const float*)d_in[5];
  const float* bv = (const float*)d_in[6];
  float* out = (float*)d_out;

  unsigned short* h_bf  = (unsigned short*)d_ws;                 // 16 MB
  unsigned short* wt_bf = h_bf + (size_t)M_TOT * K_DIM;          //  6 MB
  unsigned short* qk    = wt_bf + (size_t)N_QKV * K_DIM;         // 32 MB
  unsigned short* vtg   = qk + (size_t)M_TOT * N_QK;             // 16 MB  (total 70 MB)

  cvt_all<<<8192 + 3072, 256, 0, stream>>>(h, h_bf, Wq, Wk, Wv, wt_bf);
  qkv_gemm<<<dim3(12, 64), 512, 0, stream>>>(h_bf, wt_bf, bq, bk, bv, qk, vtg);
  attn<<<dim3(SEQ / 64, NHEAD, BSZ), 256, 0, stream>>>(qk, vtg, out);
}